// Round 9
// baseline (133.197 us; speedup 1.0000x reference)
//
#include <hip/hip_runtime.h>
#include <stdint.h>

#define NM 2048

typedef _Float16 f16;
typedef __attribute__((ext_vector_type(8))) _Float16 half8;
typedef __attribute__((ext_vector_type(4))) float float4v;

// X = A - A^T -> f16 (exactly skew; |X| <~ 0.1 so f16 abs err < 4e-5/entry)
__global__ void skew_f16_kernel(const float* __restrict__ A, f16* __restrict__ X) {
    __shared__ float t[32][33];
    const int bx = blockIdx.x * 32, by = blockIdx.y * 32;
    const int tx = threadIdx.x, ty = threadIdx.y;
    #pragma unroll
    for (int r = 0; r < 32; r += 8)
        t[ty + r][tx] = A[(size_t)(bx + ty + r) * NM + by + tx];
    __syncthreads();
    #pragma unroll
    for (int r = 0; r < 32; r += 8) {
        const int i = by + ty + r, j = bx + tx;
        X[(size_t)i * NM + j] = (f16)(A[(size_t)i * NM + j] - t[tx][ty + r]);
    }
}

// Degree-4 Paterson-Stockmeyer, two fused-epilogue GEMMs:
//   MODE 0: P = A*BT^T with A=BT=X -> v = -P = X2. Writes X2 (f16) and
//           CT = 256*C^T = (f16)(256*(v/24 - X/6))  (C = X/6 + X2/24).
//   MODE 1: A=X2, BT=CT -> v = 256*(X2*C). Writes OUT = I + X + X2/2 + v/256 (fp32).
// Core: PRODUCER-CONSUMER waves. 384 threads = 6 waves: waves 0-3 consume
// (2x2 grid of 64x64 wave tiles, 4x4 16x16x32 frags), waves 4-5 produce
// (stage A+B 128x64 tiles via global_load_lds, 16B chunks, XOR-swizzled).
// __syncthreads drains vmcnt only on producer waves -> consumers never eat
// the vmem drain; producer latency hides under the ~900cy consumer phase.
// BK=64, 32 iters, double-buffered LDS (2 x 32 KB).
template <int MODE>
__global__ __launch_bounds__(384, 1) void gemm_ps_kernel(
    const f16* __restrict__ Ap, const f16* __restrict__ BT,
    const f16* __restrict__ Xp, f16* __restrict__ X2p,
    f16* __restrict__ CTp, float* __restrict__ OUT) {
    constexpr int PLH = 128 * 64;    // halfs per plane-tile (16 KB)
    constexpr int BUFH = 2 * PLH;    // halfs per buffer (32 KB)
    __shared__ __align__(16) f16 smem[2 * BUFH];  // 64 KB

    const int tid = threadIdx.x;
    const int wave = tid >> 6, lane = tid & 63;
    const bool producer = wave >= 4;
    const int l15 = lane & 15, qq = lane >> 4;
    const int wr = (wave >> 1) & 1, wc = wave & 1;  // consumer 2x2 grid

    // XCD swizzle: 8x4 tile rectangle per XCD (bid&7 -> XCD round-robin assumed)
    const int bid = blockIdx.x;
    const int xcd = bid & 7, li = bid >> 3;
    const int by = (xcd >> 2) * 8 + (li >> 2);
    const int bx = (xcd & 3) * 4 + (li & 3);
    const int rowBase = by * 128, colBase = bx * 128;

    // ---- producer setup: 2048 chunks/buffer over 2 waves x 64 lanes x 16 issues.
    // Plane p (0=A,1=B), row m, physical slot sp holds logical k-chunk sl = sp^(m&7).
    const int pw = wave - 4;
    const f16* gsrc[16];
    int ldsoff[16];
    #pragma unroll
    for (int i = 0; i < 16; ++i) {
        const int c = i * 128 + (pw & 1) * 64 + lane;   // pw&1 keeps it sane for consumers
        const int p = c >> 10, cc = c & 1023;
        const int m = cc >> 3, sp = cc & 7;
        const int sl = sp ^ (m & 7);
        ldsoff[i] = p * PLH + cc * 8;
        gsrc[i] = (p ? BT + (size_t)(colBase + m) * NM
                     : Ap + (size_t)(rowBase + m) * NM) + sl * 8;
    }
    auto stage = [&](int buf) {
        f16* base = smem + buf * BUFH;
        #pragma unroll
        for (int i = 0; i < 16; ++i) {
            __builtin_amdgcn_global_load_lds(
                (const __attribute__((address_space(1))) void*)gsrc[i],
                (__attribute__((address_space(3))) void*)(uintptr_t)(base + ldsoff[i]),
                16, 0, 0);
            gsrc[i] += 64;
        }
    };

    // ---- consumer setup: fragment LDS offsets (halfs), 2 k-steps per iter.
    int offA[4][2], offB[4][2];
    #pragma unroll
    for (int r = 0; r < 4; ++r)
        #pragma unroll
        for (int ks = 0; ks < 2; ++ks) {
            const int m = wr * 64 + r * 16 + l15;
            offA[r][ks] = (m * 8 + ((ks * 4 + qq) ^ (m & 7))) * 8;
            const int n = wc * 64 + r * 16 + l15;
            offB[r][ks] = PLH + (n * 8 + ((ks * 4 + qq) ^ (n & 7))) * 8;
        }

    float4v acc[4][4];
    #pragma unroll
    for (int r = 0; r < 4; ++r)
        #pragma unroll
        for (int c = 0; c < 4; ++c)
            acc[r][c] = (float4v){0.f, 0.f, 0.f, 0.f};

    if (producer) stage(0);

    for (int k = 0; k < 32; ++k) {
        __syncthreads();
        if (producer) {
            if (k < 31) stage((k + 1) & 1);
        } else {
            const f16* buf = smem + (k & 1) * BUFH;
            #pragma unroll
            for (int ks = 0; ks < 2; ++ks) {
                half8 ah[4], bh[4];
                #pragma unroll
                for (int r = 0; r < 4; ++r) ah[r] = *(const half8*)&buf[offA[r][ks]];
                #pragma unroll
                for (int c = 0; c < 4; ++c) bh[c] = *(const half8*)&buf[offB[c][ks]];
                #pragma unroll
                for (int r = 0; r < 4; ++r)
                    #pragma unroll
                    for (int c = 0; c < 4; ++c)
                        acc[r][c] = __builtin_amdgcn_mfma_f32_16x16x32_f16(ah[r], bh[c], acc[r][c], 0, 0, 0);
            }
        }
    }

    if (!producer) {
        // C/D layout: col = lane&15, row = (lane>>4)*4 + reg
        #pragma unroll
        for (int r = 0; r < 4; ++r)
            #pragma unroll
            for (int c = 0; c < 4; ++c)
                #pragma unroll
                for (int g = 0; g < 4; ++g) {
                    const int row = rowBase + wr * 64 + r * 16 + qq * 4 + g;
                    const int col = colBase + wc * 64 + c * 16 + l15;
                    const size_t off = (size_t)row * NM + col;
                    float v = acc[r][c][g];
                    if (MODE == 0) {
                        v = -v;  // A*X^T = -A*X for skew X -> v = X2
                        const float x = (float)Xp[off];
                        X2p[off] = (f16)v;
                        CTp[off] = (f16)(v * (256.0f / 24.0f) - x * (256.0f / 6.0f));
                    } else {
                        const float x = (float)Xp[off];
                        const float x2 = (float)X2p[off];
                        float o = x + 0.5f * x2 + v * (1.0f / 256.0f);
                        if (row == col) o += 1.0f;
                        OUT[off] = o;
                    }
                }
    }
}

extern "C" void kernel_launch(void* const* d_in, const int* in_sizes, int n_in,
                              void* d_out, int out_size, void* d_ws, size_t ws_size,
                              hipStream_t stream) {
    const float* A = (const float*)d_in[0];
    float* out = (float*)d_out;
    const size_t NN = (size_t)NM * NM;

    // ws: 3 f16 planes (25.2 MB). d_out only written, never read.
    f16* X  = (f16*)d_ws;
    f16* X2 = X + NN;
    f16* CT = X2 + NN;

    dim3 tb(32, 8);
    dim3 tg(NM / 32, NM / 32);

    // exp(S) ~= T4(S) = (I + X + X2/2) + X2*C,  C = X/6 + X2/24.
    // 1) X = A - A^T
    skew_f16_kernel<<<tg, tb, 0, stream>>>(A, X);
    // 2) X2 = X*X; epilogue also emits CT = 256*C^T
    gemm_ps_kernel<0><<<256, 384, 0, stream>>>(X, X, X, X2, CT, nullptr);
    // 3) Y = X2*C; epilogue emits OUT = I + X + X2/2 + Y (fp32)
    gemm_ps_kernel<1><<<256, 384, 0, stream>>>(X2, CT, X, X2, nullptr, out);
}